// Round 12
// baseline (201.537 us; speedup 1.0000x reference)
//
#include <hip/hip_runtime.h>
#include <math.h>

#define NN 12288
#define EE 196608
#define FIN 128
#define AD 256
#define NG 8
#define ACH 16   // chunks per graph for adjnew/hout partials
#define GCH 16   // chunks per graph for g2 partials
#define BCAP 128 // bucket capacity per node (deg ~ Poisson(16); P(deg>128) ~ 0)
// partial-chunk pitches padded +64 floats (256 B) to break 32KB power-of-2 stride
// (HBM channel aliasing made k_red3 run at 147 GB/s)
#define APITCH 8256
#define HPITCH 4160
#define GPITCH 1088

using short8 = __attribute__((ext_vector_type(8))) short;
using floatx4 = __attribute__((ext_vector_type(4))) float;

__device__ __forceinline__ unsigned short f2bf(float f) {
  union { float f; unsigned u; } v; v.f = f;
  unsigned r = v.u + 0x7FFFu + ((v.u >> 16) & 1u);   // round-to-nearest-even
  return (unsigned short)(r >> 16);
}

// ---------------- fused setup: weights, bias, counters, gstart ----------------

__global__ __launch_bounds__(256) void k_setup(const float* __restrict__ We, const float* __restrict__ be,
    const float* __restrict__ Wp, const float* __restrict__ bp, const int* __restrict__ batch,
    unsigned* cnt_dst, unsigned* cnt_src, double* acc, unsigned* done,
    unsigned short* __restrict__ WTb, float* __restrict__ bcat, int* __restrict__ gstart) {
  unsigned i = blockIdx.x * 256u + threadIdx.x;
  if (i < 384u * 256u) {
    unsigned n = i >> 8, k = i & 255u;
    float v = (n < 128u) ? We[k * 128u + n] : Wp[k * 256u + (n - 128u)];
    WTb[i] = f2bf(v);
  }
  if (i < 384u) bcat[i] = (i < 128u) ? be[i] : bp[i - 128u];
  if (i < NN) { cnt_dst[i] = 0u; cnt_src[i] = 0u; }
  if (i < 3u) acc[i] = 0.0;
  if (i == 3u) *done = 0u;
  if (i <= NG) {   // batch sorted: binary-search graph boundaries
    int g = (int)i, lo = 0, hi = NN;
    while (lo < hi) { int mid = (lo + hi) >> 1; if (batch[mid] < g) lo = mid + 1; else hi = mid; }
    gstart[g] = lo;
  }
}

// ---------------- one-pass padded-bucket edge scatter ----------------
// bsrc entries pack the dst graph id: (batch[d]<<14)|d  (NN=12288 < 2^14)

__global__ __launch_bounds__(256) void k_edgeB(const int* __restrict__ src, const int* __restrict__ dst,
    const int* __restrict__ batch,
    unsigned* cnt_dst, unsigned* cnt_src, int* __restrict__ bdst, int* __restrict__ bsrc) {
  unsigned e = blockIdx.x * 256u + threadIdx.x;
  if (e >= EE) return;
  int s = src[e], d = dst[e];
  unsigned p = atomicAdd(&cnt_dst[d], 1u);
  if (p < BCAP) bdst[(size_t)d * BCAP + p] = s;
  int gd = batch[d];
  unsigned q = atomicAdd(&cnt_src[s], 1u);
  if (q < BCAP) bsrc[(size_t)s * BCAP + q] = (gd << 14) | d;
}

// ---------------- fused: dup-count (||A||^2) + mean aggregation -> Zb bf16 ----------------

__global__ __launch_bounds__(256) void k_dupagg(const float* __restrict__ x,
    const unsigned* __restrict__ cnt_dst, const int* __restrict__ bdst,
    unsigned short* __restrict__ Zb, unsigned* __restrict__ dup_part) {
  int node = blockIdx.x * 4 + (threadIdx.x >> 6);
  int lane = threadIdx.x & 63;
  unsigned deg = cnt_dst[node];
  unsigned m = deg < BCAP ? deg : BCAP;
  const int* bk = bdst + (size_t)node * BCAP;
  unsigned cnt = 0;
  for (unsigned i0 = 0; i0 < m; i0 += 64) {
    int si = (i0 + lane < m) ? bk[i0 + lane] : -1;
    for (unsigned j = 0; j < m; j++) {
      int sj = bk[j];
      cnt += (si == sj) ? 1u : 0u;
    }
  }
#pragma unroll
  for (int o = 32; o >= 1; o >>= 1) cnt += __shfl_xor(cnt, o, 64);
  if (lane == 0) dup_part[node] = cnt;
  const float2* x2 = (const float2*)x;
  float ax = 0.f, ay = 0.f;
  for (unsigned k = 0; k < m; k++) {
    int s = bk[k];
    float2 v = x2[(size_t)s * 64 + lane];
    ax += v.x; ay += v.y;
  }
  float inv = 1.f / fmaxf((float)deg, 1.f);
  float2 sv = x2[(size_t)node * 64 + lane];
  ushort2* Zb2 = (ushort2*)Zb;
  ushort2 a; a.x = f2bf(sv.x); a.y = f2bf(sv.y);
  ushort2 mm; mm.x = f2bf(ax * inv); mm.y = f2bf(ay * inv);
  Zb2[(size_t)node * 128 + lane] = a;
  Zb2[(size_t)node * 128 + 64 + lane] = mm;
}

// ---------------- fused MFMA GEMM + normalize + block softmax (register epilogue) ----------------
// 64 rows x 384 cols per block; wave w owns rows [16w,16w+16) x ALL 24 col-tiles.
// Row lives in one 16-lane group (col=lane&15, row=quad*4+reg): norms/softmax via shuffles.

__global__ __launch_bounds__(256) void k_gemmnorm(const unsigned short* __restrict__ Zb,
    const unsigned short* __restrict__ WTb, const float* __restrict__ bcat,
    const int* __restrict__ batch, float* __restrict__ embed, float* __restrict__ Rc) {
  __shared__ unsigned short Bl[24 * 512];   // 24 KB: tile x lane-frag
  __shared__ unsigned short Al[4 * 512];    // 4 KB:  strip x lane-frag
  int t = threadIdx.x;
  int gm = blockIdx.x * 64;
  int w = t >> 6, l = t & 63;

  floatx4 acc[24] = {};

  for (int kc = 0; kc < 8; kc++) {
    __syncthreads();
#pragma unroll
    for (int i = 0; i < 7; i++) {
      int p = t + i * 256;
      if (p < 1536) {          // B: n = p>>2 (0..383), quad = p&3
        int n = p >> 2, quad = p & 3;
        uint4 v = *(const uint4*)&WTb[(size_t)n * 256 + kc * 32 + quad * 8];
        *(uint4*)&Bl[(n >> 4) * 512 + ((n & 15) + 16 * quad) * 8] = v;
      } else {                 // A: m = (p-1536)>>2 (0..63)
        int p2 = p - 1536;
        int m = p2 >> 2, quad = p2 & 3;
        uint4 v = *(const uint4*)&Zb[(size_t)(gm + m) * 256 + kc * 32 + quad * 8];
        *(uint4*)&Al[(m >> 4) * 512 + ((m & 15) + 16 * quad) * 8] = v;
      }
    }
    __syncthreads();
    short8 a = *(const short8*)&Al[w * 512 + l * 8];
#pragma unroll
    for (int tt = 0; tt < 24; tt++) {
      short8 b = *(const short8*)&Bl[tt * 512 + l * 8];
      acc[tt] = __builtin_amdgcn_mfma_f32_16x16x32_bf16(a, b, acc[tt], 0, 0, 0);
    }
  }

  int col16 = l & 15, quad = l >> 4;
#pragma unroll
  for (int tt = 0; tt < 24; tt++) {
    float b = bcat[tt * 16 + col16];
    acc[tt][0] += b; acc[tt][1] += b; acc[tt][2] += b; acc[tt][3] += b;
  }

#pragma unroll
  for (int r = 0; r < 4; r++) {
    int node = gm + w * 16 + quad * 4 + r;
    float ss = 0.f;
#pragma unroll
    for (int tt = 0; tt < 8; tt++) { float v = acc[tt][r]; ss += v * v; }
#pragma unroll
    for (int o = 8; o >= 1; o >>= 1) ss += __shfl_xor(ss, o, 64);
    float inv = 1.f / fmaxf(sqrtf(ss), 1e-12f);
#pragma unroll
    for (int tt = 0; tt < 8; tt++)
      embed[(size_t)node * 128 + tt * 16 + col16] = acc[tt][r] * inv;
    float ss2 = 0.f;
#pragma unroll
    for (int tt = 8; tt < 24; tt++) { float v = acc[tt][r]; ss2 += v * v; }
#pragma unroll
    for (int o = 8; o >= 1; o >>= 1) ss2 += __shfl_xor(ss2, o, 64);
    float inv2 = 1.f / fmaxf(sqrtf(ss2), 1e-12f);
    int g = batch[node];
    float v0 = 0.f, v1 = 0.f;
#pragma unroll
    for (int tg = 0; tg < 8; tg++) {
      bool sel = (tg == g);
      v0 = sel ? acc[8 + 2 * tg][r] : v0;
      v1 = sel ? acc[9 + 2 * tg][r] : v1;
    }
    v0 *= inv2; v1 *= inv2;
    float mx = fmaxf(v0, v1);
#pragma unroll
    for (int o = 8; o >= 1; o >>= 1) mx = fmaxf(mx, __shfl_xor(mx, o, 64));
    float e0 = expf(v0 - mx), e1 = expf(v1 - mx);
    float sm = e0 + e1;
#pragma unroll
    for (int o = 8; o >= 1; o >>= 1) sm += __shfl_xor(sm, o, 64);
    float rr = 1.f / sm;
    Rc[(size_t)node * 32 + col16] = e0 * rr;
    Rc[(size_t)node * 32 + 16 + col16] = e1 * rr;
  }
}

// ---------------- Ar[i,:] = sum over out-edges of R[dst,:] ----------------
// One 8-lane subgroup per node: per edge, the subgroup's 8 lanes load the dst
// row's full 32 floats (128B, ALL lanes active). Per-graph accumulation in
// registers via unrolled select (8 x float4); no LDS, no atomics.

__global__ __launch_bounds__(256) void k_ar(const float* __restrict__ Rc,
    const unsigned* __restrict__ cnt_src, const int* __restrict__ bsrc,
    float* __restrict__ Ar) {
  int w = threadIdx.x >> 6, l = threadIdx.x & 63;
  int sub = l >> 3, li = l & 7;
  int node = blockIdx.x * 32 + w * 8 + sub;
  unsigned deg = cnt_src[node];              // uniform within subgroup
  unsigned m = deg < BCAP ? deg : BCAP;
  const int* bk = bsrc + (size_t)node * BCAP;
  const float4* R4 = (const float4*)Rc;
  float4 acc[8] = {};
  // uniform loop bound: wave-max of per-subgroup m
  unsigned mmax = m;
#pragma unroll
  for (int o = 8; o < 64; o <<= 1) {
    unsigned v = (unsigned)__shfl_xor((int)mmax, o, 64);
    mmax = mmax > v ? mmax : v;
  }
  for (unsigned k = 0; k < mmax; k++) {
    if (k < m) {
      int packed = bk[k];
      int d = packed & 16383, g = packed >> 14;
      float4 r = R4[(size_t)d * 8 + li];
#pragma unroll
      for (int gg = 0; gg < 8; gg++) {
        bool s = (gg == g);
        acc[gg].x += s ? r.x : 0.f;
        acc[gg].y += s ? r.y : 0.f;
        acc[gg].z += s ? r.z : 0.f;
        acc[gg].w += s ? r.w : 0.f;
      }
    }
  }
#pragma unroll
  for (int gg = 0; gg < 8; gg++)
    *(float4*)&Ar[(size_t)node * 256 + gg * 32 + li * 4] = acc[gg];
}

// ---------------- fused R^T-GEMM partials: role 0 = hout, 1 = adjnew, 2 = g2 ----------------

__global__ __launch_bounds__(256) void k_big3(const float* __restrict__ Rc,
    const float* __restrict__ embed, const float* __restrict__ Ar, const int* __restrict__ gstart,
    float* __restrict__ part_h, float* __restrict__ part_adj, float* __restrict__ Gpart) {
  int role = blockIdx.z;
  int g = blockIdx.x, ch = blockIdx.y;
  int s0 = gstart[g], e0 = gstart[g + 1];
  int nch = (role == 2) ? GCH : ACH;
  int per = (e0 - s0 + nch - 1) / nch;
  int i0 = s0 + ch * per;
  int i1 = i0 + per; if (i1 > e0) i1 = e0;
  int t = threadIdx.x;
  __shared__ float rcs[128][32];   // 16 KB; roles 0/1 use first 64 rows

  if (role == 0) {
    int f4 = t & 31, c1g = t >> 5;
    float4 acc[4] = {};
    const float4* E4 = (const float4*)embed;
    for (int ib = i0; ib < i1; ib += 64) {
      int cnt = i1 - ib; if (cnt > 64) cnt = 64;
      __syncthreads();
      const float4* s4 = (const float4*)(Rc + (size_t)ib * 32);
      for (int idx = t; idx < cnt * 8; idx += 256) ((float4*)rcs)[idx] = s4[idx];
      __syncthreads();
      for (int n = 0; n < cnt; n++) {
        float4 e4 = E4[(size_t)(ib + n) * 32 + f4];
        float4 r = *(const float4*)&rcs[n][c1g * 4];
        float rv[4] = {r.x, r.y, r.z, r.w};
#pragma unroll
        for (int j = 0; j < 4; j++) {
          acc[j].x += rv[j] * e4.x; acc[j].y += rv[j] * e4.y;
          acc[j].z += rv[j] * e4.z; acc[j].w += rv[j] * e4.w;
        }
      }
    }
    float* p = part_h + (size_t)(g * ACH + ch) * HPITCH;
#pragma unroll
    for (int j = 0; j < 4; j++)
      *(float4*)&p[(c1g * 4 + j) * 128 + f4 * 4] = acc[j];
  } else if (role == 1) {
    int c2q = t & 63, c1g = t >> 6;
    float4 acc[8] = {};
    const float4* Ar4 = (const float4*)Ar;
    for (int ib = i0; ib < i1; ib += 64) {
      int cnt = i1 - ib; if (cnt > 64) cnt = 64;
      __syncthreads();
      const float4* s4 = (const float4*)(Rc + (size_t)ib * 32);
      for (int idx = t; idx < cnt * 8; idx += 256) ((float4*)rcs)[idx] = s4[idx];
      __syncthreads();
      for (int n = 0; n < cnt; n++) {
        float4 a4 = Ar4[(size_t)(ib + n) * 64 + c2q];
        float4 r0 = *(const float4*)&rcs[n][c1g * 8];
        float4 r1 = *(const float4*)&rcs[n][c1g * 8 + 4];
        float rv[8] = {r0.x, r0.y, r0.z, r0.w, r1.x, r1.y, r1.z, r1.w};
#pragma unroll
        for (int j = 0; j < 8; j++) {
          acc[j].x += rv[j] * a4.x; acc[j].y += rv[j] * a4.y;
          acc[j].z += rv[j] * a4.z; acc[j].w += rv[j] * a4.w;
        }
      }
    }
    float* p = part_adj + (size_t)(g * ACH + ch) * APITCH;
#pragma unroll
    for (int j = 0; j < 8; j++)
      *(float4*)&p[(c1g * 8 + j) * 256 + c2q * 4] = acc[j];
  } else {
    int c2q = t & 7, c1 = t >> 3;
    float4 acc = {};
    for (int ib = i0; ib < i1; ib += 128) {
      int cnt = i1 - ib; if (cnt > 128) cnt = 128;
      __syncthreads();
      const float4* s4 = (const float4*)(Rc + (size_t)ib * 32);
      for (int idx = t; idx < cnt * 8; idx += 256) ((float4*)rcs)[idx] = s4[idx];
      __syncthreads();
      for (int n = 0; n < cnt; n++) {
        float4 r2 = *(const float4*)&rcs[n][c2q * 4];
        float r1 = rcs[n][c1];
        acc.x += r1 * r2.x; acc.y += r1 * r2.y; acc.z += r1 * r2.z; acc.w += r1 * r2.w;
      }
    }
    *(float4*)&Gpart[(size_t)(g * GCH + ch) * GPITCH + c1 * 32 + c2q * 4] = acc;
  }
}

// ---------------- fused reduce + loss scalars (last-block writes the final outputs) ----------------

__global__ __launch_bounds__(256) void k_red3(const float* __restrict__ part_adj,
    const float* __restrict__ part_h, const float* __restrict__ Gpart,
    const unsigned* __restrict__ dup_part,
    float* __restrict__ outa, float* __restrict__ outh,
    double* __restrict__ acc, unsigned* __restrict__ done, float* __restrict__ out) {
  int b = blockIdx.x, t = threadIdx.x;
  int lane = t & 63;
  if (b < 256) {
    int i = b * 256 + t;
    int g = i >> 13, off = i & 8191;
    const float* base = part_adj + (size_t)g * ACH * APITCH + off;
    float s = 0.f;
#pragma unroll
    for (int ch = 0; ch < ACH; ch++) s += base[(size_t)ch * APITCH];
    outa[i] = s;
    if (t == b) atomicAdd(&acc[0], (double)s);   // row b, col t: diagonal
  } else if (b < 384) {
    int j = (b - 256) * 256 + t;
    int g = j >> 12, off = j & 4095;
    const float* base = part_h + (size_t)g * ACH * HPITCH + off;
    float s = 0.f;
#pragma unroll
    for (int ch = 0; ch < ACH; ch++) s += base[(size_t)ch * HPITCH];
    outh[j] = s;
  } else if (b < 416) {
    int j = (b - 384) * 256 + t;
    int g = j >> 10, off = j & 1023;
    const float* base = Gpart + (size_t)g * GCH * GPITCH + off;
    float s = 0.f;
#pragma unroll
    for (int ch = 0; ch < GCH; ch++) s += base[(size_t)ch * GPITCH];
    double g2 = (double)s * (double)s;
#pragma unroll
    for (int o = 32; o >= 1; o >>= 1) g2 += __shfl_xor(g2, o, 64);
    if (lane == 0) atomicAdd(&acc[1], g2);
  } else {
    int j = (b - 416) * 256 + t;
    double a2 = (double)dup_part[j];
#pragma unroll
    for (int o = 32; o >= 1; o >>= 1) a2 += __shfl_xor(a2, o, 64);
    if (lane == 0) atomicAdd(&acc[2], a2);
  }
  __syncthreads();   // drains vmcnt: this block's atomics are globally performed
  if (t == 0) {
    unsigned prev = atomicAdd(done, 1u);
    if (prev == gridDim.x - 1) {
      double trf = atomicAdd(&acc[0], 0.0);
      double g2f = atomicAdd(&acc[1], 0.0);
      double a2f = atomicAdd(&acc[2], 0.0);
      double val = a2f - 2.0 * trf + g2f;   // ||A - RR^T||_F^2
      if (val < 0.0) val = 0.0;
      out[98304] = (float)(sqrt(val) / ((double)NN * (double)NN));
      out[98305] = (float)((double)NN * log(32.0));
    }
  }
}

// ---------------- launch ----------------

extern "C" void kernel_launch(void* const* d_in, const int* in_sizes, int n_in,
                              void* d_out, int out_size, void* d_ws, size_t ws_size,
                              hipStream_t stream) {
  const float* x = (const float*)d_in[0];
  const int* ei = (const int*)d_in[1];
  const int* src = ei;
  const int* dst = ei + EE;
  const int* batch = (const int*)d_in[2];
  const float* Wemb = (const float*)d_in[3];
  const float* bemb = (const float*)d_in[4];
  const float* Wpool = (const float*)d_in[5];
  const float* bpool = (const float*)d_in[6];
  float* out = (float*)d_out;

  char* w = (char*)d_ws;
  size_t off = 0;
  auto A = [&](size_t bytes) -> char* {
    char* p = w + off;
    off += (bytes + 255) & ~(size_t)255;
    return p;
  };
  unsigned* cnt_dst = (unsigned*)A(NN * 4);
  unsigned* cnt_src = (unsigned*)A(NN * 4);
  int* bdst = (int*)A((size_t)NN * BCAP * 4);   // 6.3 MB
  int* bsrc = (int*)A((size_t)NN * BCAP * 4);   // 6.3 MB
  int* gstart = (int*)A(64);
  unsigned* dup_part = (unsigned*)A(NN * 4);
  double* acc = (double*)A(3 * 8);
  unsigned* done = (unsigned*)A(4);
  unsigned short* Zb = (unsigned short*)A((size_t)NN * 256 * 2);  // 6.3 MB bf16
  float* embed = (float*)A((size_t)NN * FIN * 4);                 // 6.3 MB
  float* Rc = (float*)A((size_t)NN * 32 * 4);                     // 1.6 MB
  float* Ar = (float*)A((size_t)NN * AD * 4);                     // 12.6 MB
  unsigned short* WTb = (unsigned short*)A(384 * 256 * 2);
  float* bcat = (float*)A(384 * 4);
  float* part_h = (float*)A((size_t)8 * ACH * HPITCH * 4);        // 2.1 MB
  float* part_adj = (float*)A((size_t)8 * ACH * APITCH * 4);      // 4.1 MB
  float* Gpart = (float*)A((size_t)8 * GCH * GPITCH * 4);         // 545 KB
  (void)ws_size; (void)in_sizes; (void)n_in; (void)out_size;      // ~47 MB

  k_setup<<<dim3(384), dim3(256), 0, stream>>>(Wemb, bemb, Wpool, bpool, batch,
      cnt_dst, cnt_src, acc, done, WTb, bcat, gstart);
  k_edgeB<<<dim3(EE / 256), dim3(256), 0, stream>>>(src, dst, batch, cnt_dst, cnt_src, bdst, bsrc);
  k_dupagg<<<dim3(NN / 4), dim3(256), 0, stream>>>(x, cnt_dst, bdst, Zb, dup_part);
  k_gemmnorm<<<dim3(NN / 64), dim3(256), 0, stream>>>(Zb, WTb, bcat, batch, embed, Rc);
  k_ar<<<dim3(NN / 32), dim3(256), 0, stream>>>(Rc, cnt_src, bsrc, Ar);
  k_big3<<<dim3(8, ACH, 3), dim3(256), 0, stream>>>(Rc, embed, Ar, gstart, part_h, part_adj, Gpart);
  k_red3<<<dim3(464), dim3(256), 0, stream>>>(part_adj, part_h, Gpart, dup_part,
      out, out + 65536, acc, done, out);
}

// Round 13
// 190.168 us; speedup vs baseline: 1.0598x; 1.0598x over previous
//
#include <hip/hip_runtime.h>
#include <math.h>

#define NN 12288
#define EE 196608
#define FIN 128
#define AD 256
#define NG 8
#define ACH 32   // chunks per graph for adjnew/hout partials
#define GCH 16   // chunks per graph for g2 partials
#define BCAP 128 // bucket capacity per node (deg ~ Poisson(16); P(deg>128) ~ 0)
// partial-chunk pitches padded +64 floats (256 B) to break 32KB power-of-2 stride
// (HBM channel aliasing made k_red3 run at 147 GB/s)
#define APITCH 8256
#define HPITCH 4160
#define GPITCH 1088

using short8 = __attribute__((ext_vector_type(8))) short;
using floatx4 = __attribute__((ext_vector_type(4))) float;

__device__ __forceinline__ unsigned short f2bf(float f) {
  union { float f; unsigned u; } v; v.f = f;
  unsigned r = v.u + 0x7FFFu + ((v.u >> 16) & 1u);   // round-to-nearest-even
  return (unsigned short)(r >> 16);
}

// ---------------- fused setup: weights, bias, counters, gstart ----------------

__global__ __launch_bounds__(256) void k_setup(const float* __restrict__ We, const float* __restrict__ be,
    const float* __restrict__ Wp, const float* __restrict__ bp, const int* __restrict__ batch,
    unsigned* cnt_dst, unsigned* cnt_src, double* acc, unsigned* done,
    unsigned short* __restrict__ WTb, float* __restrict__ bcat, int* __restrict__ gstart) {
  unsigned i = blockIdx.x * 256u + threadIdx.x;
  if (i < 384u * 256u) {
    unsigned n = i >> 8, k = i & 255u;
    float v = (n < 128u) ? We[k * 128u + n] : Wp[k * 256u + (n - 128u)];
    WTb[i] = f2bf(v);
  }
  if (i < 384u) bcat[i] = (i < 128u) ? be[i] : bp[i - 128u];
  if (i < NN) { cnt_dst[i] = 0u; cnt_src[i] = 0u; }
  if (i < 3u) acc[i] = 0.0;
  if (i == 3u) *done = 0u;
  if (i <= NG) {   // batch sorted: binary-search graph boundaries
    int g = (int)i, lo = 0, hi = NN;
    while (lo < hi) { int mid = (lo + hi) >> 1; if (batch[mid] < g) lo = mid + 1; else hi = mid; }
    gstart[g] = lo;
  }
}

// ---------------- one-pass padded-bucket edge scatter ----------------
// bsrc entries pack the dst graph id: (batch[d]<<14)|d  (NN=12288 < 2^14)

__global__ __launch_bounds__(256) void k_edgeB(const int* __restrict__ src, const int* __restrict__ dst,
    const int* __restrict__ batch,
    unsigned* cnt_dst, unsigned* cnt_src, int* __restrict__ bdst, int* __restrict__ bsrc) {
  unsigned e = blockIdx.x * 256u + threadIdx.x;
  if (e >= EE) return;
  int s = src[e], d = dst[e];
  unsigned p = atomicAdd(&cnt_dst[d], 1u);
  if (p < BCAP) bdst[(size_t)d * BCAP + p] = s;
  int gd = batch[d];
  unsigned q = atomicAdd(&cnt_src[s], 1u);
  if (q < BCAP) bsrc[(size_t)s * BCAP + q] = (gd << 14) | d;
}

// ---------------- fused: dup-count (||A||^2) + mean aggregation -> Zb bf16 ----------------
// single loop: the broadcast bk[j] load serves both the equality count and the
// gather index (was two separate m-iteration loops)

__global__ __launch_bounds__(256) void k_dupagg(const float* __restrict__ x,
    const unsigned* __restrict__ cnt_dst, const int* __restrict__ bdst,
    unsigned short* __restrict__ Zb, unsigned* __restrict__ dup_part) {
  int node = blockIdx.x * 4 + (threadIdx.x >> 6);
  int lane = threadIdx.x & 63;
  unsigned deg = cnt_dst[node];
  unsigned m = deg < BCAP ? deg : BCAP;
  const int* bk = bdst + (size_t)node * BCAP;
  const float2* x2 = (const float2*)x;
  unsigned cnt = 0;
  float ax = 0.f, ay = 0.f;
  int si = ((unsigned)lane < m) ? bk[lane] : -2;
  for (unsigned j = 0; j < m; j++) {
    int sj = bk[j];                          // broadcast (wave-uniform)
    cnt += (si == sj) ? 1u : 0u;
    float2 v = x2[(size_t)sj * 64 + lane];   // agg gather
    ax += v.x; ay += v.y;
  }
  // tail for deg>64 (statistically never; correctness guard)
  for (unsigned i0 = 64; i0 < m; i0 += 64) {
    int si2 = (i0 + lane < m) ? bk[i0 + lane] : -2;
    for (unsigned j = 0; j < m; j++) cnt += (si2 == bk[j]) ? 1u : 0u;
  }
#pragma unroll
  for (int o = 32; o >= 1; o >>= 1) cnt += __shfl_xor(cnt, o, 64);
  if (lane == 0) dup_part[node] = cnt;
  float inv = 1.f / fmaxf((float)deg, 1.f);
  float2 sv = x2[(size_t)node * 64 + lane];
  ushort2* Zb2 = (ushort2*)Zb;
  ushort2 a; a.x = f2bf(sv.x); a.y = f2bf(sv.y);
  ushort2 mm; mm.x = f2bf(ax * inv); mm.y = f2bf(ay * inv);
  Zb2[(size_t)node * 128 + lane] = a;
  Zb2[(size_t)node * 128 + 64 + lane] = mm;
}

// ---------------- fused MFMA GEMM + normalize + block softmax (register epilogue) ----------------
// 64 rows x 384 cols per block; wave w owns rows [16w,16w+16) x ALL 24 col-tiles.
// Row lives in one 16-lane group (col=lane&15, row=quad*4+reg): norms/softmax via shuffles.

__global__ __launch_bounds__(256) void k_gemmnorm(const unsigned short* __restrict__ Zb,
    const unsigned short* __restrict__ WTb, const float* __restrict__ bcat,
    const int* __restrict__ batch, float* __restrict__ embed, float* __restrict__ Rc) {
  __shared__ unsigned short Bl[24 * 512];   // 24 KB: tile x lane-frag
  __shared__ unsigned short Al[4 * 512];    // 4 KB:  strip x lane-frag
  int t = threadIdx.x;
  int gm = blockIdx.x * 64;
  int w = t >> 6, l = t & 63;

  floatx4 acc[24] = {};

  for (int kc = 0; kc < 8; kc++) {
    __syncthreads();
#pragma unroll
    for (int i = 0; i < 7; i++) {
      int p = t + i * 256;
      if (p < 1536) {          // B: n = p>>2 (0..383), quad = p&3
        int n = p >> 2, quad = p & 3;
        uint4 v = *(const uint4*)&WTb[(size_t)n * 256 + kc * 32 + quad * 8];
        *(uint4*)&Bl[(n >> 4) * 512 + ((n & 15) + 16 * quad) * 8] = v;
      } else {                 // A: m = (p-1536)>>2 (0..63)
        int p2 = p - 1536;
        int m = p2 >> 2, quad = p2 & 3;
        uint4 v = *(const uint4*)&Zb[(size_t)(gm + m) * 256 + kc * 32 + quad * 8];
        *(uint4*)&Al[(m >> 4) * 512 + ((m & 15) + 16 * quad) * 8] = v;
      }
    }
    __syncthreads();
    short8 a = *(const short8*)&Al[w * 512 + l * 8];
#pragma unroll
    for (int tt = 0; tt < 24; tt++) {
      short8 b = *(const short8*)&Bl[tt * 512 + l * 8];
      acc[tt] = __builtin_amdgcn_mfma_f32_16x16x32_bf16(a, b, acc[tt], 0, 0, 0);
    }
  }

  int col16 = l & 15, quad = l >> 4;
#pragma unroll
  for (int tt = 0; tt < 24; tt++) {
    float b = bcat[tt * 16 + col16];
    acc[tt][0] += b; acc[tt][1] += b; acc[tt][2] += b; acc[tt][3] += b;
  }

#pragma unroll
  for (int r = 0; r < 4; r++) {
    int node = gm + w * 16 + quad * 4 + r;
    float ss = 0.f;
#pragma unroll
    for (int tt = 0; tt < 8; tt++) { float v = acc[tt][r]; ss += v * v; }
#pragma unroll
    for (int o = 8; o >= 1; o >>= 1) ss += __shfl_xor(ss, o, 64);
    float inv = 1.f / fmaxf(sqrtf(ss), 1e-12f);
#pragma unroll
    for (int tt = 0; tt < 8; tt++)
      embed[(size_t)node * 128 + tt * 16 + col16] = acc[tt][r] * inv;
    float ss2 = 0.f;
#pragma unroll
    for (int tt = 8; tt < 24; tt++) { float v = acc[tt][r]; ss2 += v * v; }
#pragma unroll
    for (int o = 8; o >= 1; o >>= 1) ss2 += __shfl_xor(ss2, o, 64);
    float inv2 = 1.f / fmaxf(sqrtf(ss2), 1e-12f);
    int g = batch[node];
    float v0 = 0.f, v1 = 0.f;
#pragma unroll
    for (int tg = 0; tg < 8; tg++) {
      bool sel = (tg == g);
      v0 = sel ? acc[8 + 2 * tg][r] : v0;
      v1 = sel ? acc[9 + 2 * tg][r] : v1;
    }
    v0 *= inv2; v1 *= inv2;
    float mx = fmaxf(v0, v1);
#pragma unroll
    for (int o = 8; o >= 1; o >>= 1) mx = fmaxf(mx, __shfl_xor(mx, o, 64));
    float e0 = expf(v0 - mx), e1 = expf(v1 - mx);
    float sm = e0 + e1;
#pragma unroll
    for (int o = 8; o >= 1; o >>= 1) sm += __shfl_xor(sm, o, 64);
    float rr = 1.f / sm;
    Rc[(size_t)node * 32 + col16] = e0 * rr;
    Rc[(size_t)node * 32 + 16 + col16] = e1 * rr;
  }
}

// ---------------- Ar[i,:] = sum over out-edges of R[dst,:] (src buckets, packed g) ----------------

__global__ __launch_bounds__(256) void k_ar(const float* __restrict__ Rc,
    const unsigned* __restrict__ cnt_src, const int* __restrict__ bsrc,
    float* __restrict__ Ar) {
  int node = blockIdx.x * 4 + (threadIdx.x >> 6);
  int lane = threadIdx.x & 63;
  int lg = lane >> 3, li = lane & 7;
  unsigned deg = cnt_src[node];
  unsigned m = deg < BCAP ? deg : BCAP;
  const int* bk = bsrc + (size_t)node * BCAP;
  float4 acc = {0.f, 0.f, 0.f, 0.f};
  const float4* R4 = (const float4*)Rc;
  for (unsigned k = 0; k < m; k++) {
    int packed = bk[k];
    int d = packed & 16383, g = packed >> 14;
    if (lg == g) {
      float4 r = R4[(size_t)d * 8 + li];
      acc.x += r.x; acc.y += r.y; acc.z += r.z; acc.w += r.w;
    }
  }
  ((float4*)Ar)[(size_t)node * 64 + lane] = acc;
}

// ---------------- fused R^T-GEMM partials: role 0 = hout, 1 = adjnew, 2 = g2 ----------------

__global__ __launch_bounds__(256) void k_big3(const float* __restrict__ Rc,
    const float* __restrict__ embed, const float* __restrict__ Ar, const int* __restrict__ gstart,
    float* __restrict__ part_h, float* __restrict__ part_adj, float* __restrict__ Gpart) {
  int role = blockIdx.z;
  int g = blockIdx.x, ch = blockIdx.y;
  if (role == 2 && ch >= GCH) return;
  int s0 = gstart[g], e0 = gstart[g + 1];
  int nch = (role == 2) ? GCH : ACH;
  int per = (e0 - s0 + nch - 1) / nch;
  int i0 = s0 + ch * per;
  int i1 = i0 + per; if (i1 > e0) i1 = e0;
  int t = threadIdx.x;
  __shared__ float rcs[128][32];   // 16 KB; roles 0/1 use first 64 rows

  if (role == 0) {
    int f4 = t & 31, c1g = t >> 5;
    float4 acc[4] = {};
    const float4* E4 = (const float4*)embed;
    for (int ib = i0; ib < i1; ib += 64) {
      int cnt = i1 - ib; if (cnt > 64) cnt = 64;
      __syncthreads();
      const float4* s4 = (const float4*)(Rc + (size_t)ib * 32);
      for (int idx = t; idx < cnt * 8; idx += 256) ((float4*)rcs)[idx] = s4[idx];
      __syncthreads();
      for (int n = 0; n < cnt; n++) {
        float4 e4 = E4[(size_t)(ib + n) * 32 + f4];
        float4 r = *(const float4*)&rcs[n][c1g * 4];
        float rv[4] = {r.x, r.y, r.z, r.w};
#pragma unroll
        for (int j = 0; j < 4; j++) {
          acc[j].x += rv[j] * e4.x; acc[j].y += rv[j] * e4.y;
          acc[j].z += rv[j] * e4.z; acc[j].w += rv[j] * e4.w;
        }
      }
    }
    float* p = part_h + (size_t)(g * ACH + ch) * HPITCH;
#pragma unroll
    for (int j = 0; j < 4; j++)
      *(float4*)&p[(c1g * 4 + j) * 128 + f4 * 4] = acc[j];
  } else if (role == 1) {
    int c2q = t & 63, c1g = t >> 6;
    float4 acc[8] = {};
    const float4* Ar4 = (const float4*)Ar;
    for (int ib = i0; ib < i1; ib += 64) {
      int cnt = i1 - ib; if (cnt > 64) cnt = 64;
      __syncthreads();
      const float4* s4 = (const float4*)(Rc + (size_t)ib * 32);
      for (int idx = t; idx < cnt * 8; idx += 256) ((float4*)rcs)[idx] = s4[idx];
      __syncthreads();
      for (int n = 0; n < cnt; n++) {
        float4 a4 = Ar4[(size_t)(ib + n) * 64 + c2q];
        float4 r0 = *(const float4*)&rcs[n][c1g * 8];
        float4 r1 = *(const float4*)&rcs[n][c1g * 8 + 4];
        float rv[8] = {r0.x, r0.y, r0.z, r0.w, r1.x, r1.y, r1.z, r1.w};
#pragma unroll
        for (int j = 0; j < 8; j++) {
          acc[j].x += rv[j] * a4.x; acc[j].y += rv[j] * a4.y;
          acc[j].z += rv[j] * a4.z; acc[j].w += rv[j] * a4.w;
        }
      }
    }
    float* p = part_adj + (size_t)(g * ACH + ch) * APITCH;
#pragma unroll
    for (int j = 0; j < 8; j++)
      *(float4*)&p[(c1g * 8 + j) * 256 + c2q * 4] = acc[j];
  } else {
    int c2q = t & 7, c1 = t >> 3;
    float4 acc = {};
    for (int ib = i0; ib < i1; ib += 128) {
      int cnt = i1 - ib; if (cnt > 128) cnt = 128;
      __syncthreads();
      const float4* s4 = (const float4*)(Rc + (size_t)ib * 32);
      for (int idx = t; idx < cnt * 8; idx += 256) ((float4*)rcs)[idx] = s4[idx];
      __syncthreads();
      for (int n = 0; n < cnt; n++) {
        float4 r2 = *(const float4*)&rcs[n][c2q * 4];
        float r1 = rcs[n][c1];
        acc.x += r1 * r2.x; acc.y += r1 * r2.y; acc.z += r1 * r2.z; acc.w += r1 * r2.w;
      }
    }
    *(float4*)&Gpart[(size_t)(g * GCH + ch) * GPITCH + c1 * 32 + c2q * 4] = acc;
  }
}

// ---------------- fused reduce + loss scalars (last-block writes the final outputs) ----------------

__global__ __launch_bounds__(256) void k_red3(const float* __restrict__ part_adj,
    const float* __restrict__ part_h, const float* __restrict__ Gpart,
    const unsigned* __restrict__ dup_part,
    float* __restrict__ outa, float* __restrict__ outh,
    double* __restrict__ acc, unsigned* __restrict__ done, float* __restrict__ out) {
  int b = blockIdx.x, t = threadIdx.x;
  int lane = t & 63;
  if (b < 256) {
    int i = b * 256 + t;
    int g = i >> 13, off = i & 8191;
    const float* base = part_adj + (size_t)g * ACH * APITCH + off;
    float s = 0.f;
#pragma unroll
    for (int ch = 0; ch < ACH; ch++) s += base[(size_t)ch * APITCH];
    outa[i] = s;
    if (t == b) atomicAdd(&acc[0], (double)s);   // row b, col t: diagonal
  } else if (b < 384) {
    int j = (b - 256) * 256 + t;
    int g = j >> 12, off = j & 4095;
    const float* base = part_h + (size_t)g * ACH * HPITCH + off;
    float s = 0.f;
#pragma unroll
    for (int ch = 0; ch < ACH; ch++) s += base[(size_t)ch * HPITCH];
    outh[j] = s;
  } else if (b < 416) {
    int j = (b - 384) * 256 + t;
    int g = j >> 10, off = j & 1023;
    const float* base = Gpart + (size_t)g * GCH * GPITCH + off;
    float s = 0.f;
#pragma unroll
    for (int ch = 0; ch < GCH; ch++) s += base[(size_t)ch * GPITCH];
    double g2 = (double)s * (double)s;
#pragma unroll
    for (int o = 32; o >= 1; o >>= 1) g2 += __shfl_xor(g2, o, 64);
    if (lane == 0) atomicAdd(&acc[1], g2);
  } else {
    int j = (b - 416) * 256 + t;
    double a2 = (double)dup_part[j];
#pragma unroll
    for (int o = 32; o >= 1; o >>= 1) a2 += __shfl_xor(a2, o, 64);
    if (lane == 0) atomicAdd(&acc[2], a2);
  }
  __syncthreads();   // drains vmcnt: this block's atomics are globally performed
  if (t == 0) {
    unsigned prev = atomicAdd(done, 1u);
    if (prev == gridDim.x - 1) {
      double trf = atomicAdd(&acc[0], 0.0);
      double g2f = atomicAdd(&acc[1], 0.0);
      double a2f = atomicAdd(&acc[2], 0.0);
      double val = a2f - 2.0 * trf + g2f;   // ||A - RR^T||_F^2
      if (val < 0.0) val = 0.0;
      out[98304] = (float)(sqrt(val) / ((double)NN * (double)NN));
      out[98305] = (float)((double)NN * log(32.0));
    }
  }
}

// ---------------- launch ----------------

extern "C" void kernel_launch(void* const* d_in, const int* in_sizes, int n_in,
                              void* d_out, int out_size, void* d_ws, size_t ws_size,
                              hipStream_t stream) {
  const float* x = (const float*)d_in[0];
  const int* ei = (const int*)d_in[1];
  const int* src = ei;
  const int* dst = ei + EE;
  const int* batch = (const int*)d_in[2];
  const float* Wemb = (const float*)d_in[3];
  const float* bemb = (const float*)d_in[4];
  const float* Wpool = (const float*)d_in[5];
  const float* bpool = (const float*)d_in[6];
  float* out = (float*)d_out;

  char* w = (char*)d_ws;
  size_t off = 0;
  auto A = [&](size_t bytes) -> char* {
    char* p = w + off;
    off += (bytes + 255) & ~(size_t)255;
    return p;
  };
  unsigned* cnt_dst = (unsigned*)A(NN * 4);
  unsigned* cnt_src = (unsigned*)A(NN * 4);
  int* bdst = (int*)A((size_t)NN * BCAP * 4);   // 6.3 MB
  int* bsrc = (int*)A((size_t)NN * BCAP * 4);   // 6.3 MB
  int* gstart = (int*)A(64);
  unsigned* dup_part = (unsigned*)A(NN * 4);
  double* acc = (double*)A(3 * 8);
  unsigned* done = (unsigned*)A(4);
  unsigned short* Zb = (unsigned short*)A((size_t)NN * 256 * 2);  // 6.3 MB bf16
  float* embed = (float*)A((size_t)NN * FIN * 4);                 // 6.3 MB
  float* Rc = (float*)A((size_t)NN * 32 * 4);                     // 1.6 MB
  float* Ar = (float*)A((size_t)NN * AD * 4);                     // 12.6 MB
  unsigned short* WTb = (unsigned short*)A(384 * 256 * 2);
  float* bcat = (float*)A(384 * 4);
  float* part_h = (float*)A((size_t)8 * ACH * HPITCH * 4);        // 4.3 MB
  float* part_adj = (float*)A((size_t)8 * ACH * APITCH * 4);      // 8.5 MB
  float* Gpart = (float*)A((size_t)8 * GCH * GPITCH * 4);         // 545 KB
  (void)ws_size; (void)in_sizes; (void)n_in; (void)out_size;      // ~53 MB

  k_setup<<<dim3(384), dim3(256), 0, stream>>>(Wemb, bemb, Wpool, bpool, batch,
      cnt_dst, cnt_src, acc, done, WTb, bcat, gstart);
  k_edgeB<<<dim3(EE / 256), dim3(256), 0, stream>>>(src, dst, batch, cnt_dst, cnt_src, bdst, bsrc);
  k_dupagg<<<dim3(NN / 4), dim3(256), 0, stream>>>(x, cnt_dst, bdst, Zb, dup_part);
  k_gemmnorm<<<dim3(NN / 64), dim3(256), 0, stream>>>(Zb, WTb, bcat, batch, embed, Rc);
  k_ar<<<dim3(NN / 4), dim3(256), 0, stream>>>(Rc, cnt_src, bsrc, Ar);
  k_big3<<<dim3(8, ACH, 3), dim3(256), 0, stream>>>(Rc, embed, Ar, gstart, part_h, part_adj, Gpart);
  k_red3<<<dim3(464), dim3(256), 0, stream>>>(part_adj, part_h, Gpart, dup_part,
      out, out + 65536, acc, done, out);
}